// Round 8
// baseline (81.685 us; speedup 1.0000x reference)
//
#include <hip/hip_runtime.h>

// STFT magnitude via bf16 MFMA GEMM.
// Round 8: 32x32x16 MFMA (half the MFMA instrs, higher pipe ceiling 2382 vs
// 2075 TF) + 2 blocks/CU (256-thread blocks, TT=192, sX=80,000B) so desynced
// blocks cover each other's prologue/epilogue. Barrier-free main loop with
// distance-1 register prefetch of A (global->reg, L2-hot basis) and X
// (LDS->reg), compiler-tracked waits, one prologue barrier only.

#define FL   800
#define HOP  200
#define CUT  401
#define NS   8000000
#define NT   40001
#define KSTEPS 25            // 800/32

#define FT   64              // freq tile per block
#define TT   192             // frame tile per block
#define NTT  209             // ceil(40001/192)
#define SLICE_SH 40000       // sX shorts (need 39000; 19 full sweeps + partial)
#define XBN  8016000         // xb length in shorts
#define BB_OFF 16032000      // byte offset of bb in ws (= XBN*2)

typedef short short8 __attribute__((ext_vector_type(8)));
typedef float float4v __attribute__((ext_vector_type(4)));
typedef float f32x16 __attribute__((ext_vector_type(16)));

#define GU32 const __attribute__((address_space(1))) unsigned int*
#define LU32 __attribute__((address_space(3))) unsigned int*

__device__ inline unsigned short f2bf(float f) {
    union { float f; unsigned u; } v; v.f = f;
    unsigned r = v.u + 0x7FFFu + ((v.u >> 16) & 1u);   // RNE
    return (unsigned short)(r >> 16);
}

// ---- prep 1: x (fp32) -> xb (bf16, reflect-padded by 400) ----
__global__ void prep_x(const float* __restrict__ x, short* __restrict__ xb) {
    const int n8 = XBN / 8;
    for (int j = blockIdx.x * blockDim.x + threadIdx.x; j < n8;
         j += gridDim.x * blockDim.x) {
        const int i = j * 8;
        const int s = i - 400;
        short8 o;
        if (s >= 0 && s + 7 < NS) {
            const float4v a = *reinterpret_cast<const float4v*>(x + s);
            const float4v b = *reinterpret_cast<const float4v*>(x + s + 4);
            o[0]=f2bf(a[0]); o[1]=f2bf(a[1]); o[2]=f2bf(a[2]); o[3]=f2bf(a[3]);
            o[4]=f2bf(b[0]); o[5]=f2bf(b[1]); o[6]=f2bf(b[2]); o[7]=f2bf(b[3]);
        } else {
            #pragma unroll
            for (int q = 0; q < 8; ++q) {
                int sq = s + q;
                if (sq < 0) sq = -sq;
                else if (sq >= NS) sq = 2 * NS - 2 - sq;
                o[q] = f2bf(x[sq]);
            }
        }
        *reinterpret_cast<short8*>(xb + i) = o;
    }
}

// ---- prep 2: basis (802x800 fp32) -> bb (896x800 bf16, zero pad rows) ----
__global__ void prep_b(const float* __restrict__ basis, short* __restrict__ bb) {
    const int nch = 896 * 100;
    for (int j = blockIdx.x * blockDim.x + threadIdx.x; j < nch;
         j += gridDim.x * blockDim.x) {
        const int row = j / 100;
        const int col = (j % 100) * 8;
        short8 o;
        int src = -1;
        if (row < CUT) src = row;
        else if (row >= 448 && row < 448 + CUT) src = row - 47;
        if (src >= 0) {
            const float* p = basis + (size_t)src * 800 + col;
            const float4v a = *reinterpret_cast<const float4v*>(p);
            const float4v b = *reinterpret_cast<const float4v*>(p + 4);
            o[0]=f2bf(a[0]); o[1]=f2bf(a[1]); o[2]=f2bf(a[2]); o[3]=f2bf(a[3]);
            o[4]=f2bf(b[0]); o[5]=f2bf(b[1]); o[6]=f2bf(b[2]); o[7]=f2bf(b[3]);
        } else {
            #pragma unroll
            for (int q = 0; q < 8; ++q) o[q] = 0;
        }
        *reinterpret_cast<short8*>(bb + (size_t)row * 800 + col) = o;
    }
}

#define MF32(A, X, C) C = __builtin_amdgcn_mfma_f32_32x32x16_bf16((A), (X), (C), 0, 0, 0)

// One pipeline step. CA/CX = frags for step KS; NA/NX <- prefetch for KS+1.
// CA: [0]=real k-lo, [1]=real k-hi, [2]=imag k-lo, [3]=imag k-hi.
// CX: even = k-lo, odd = k-hi, per ni. 12 MFMAs; same-acc reuse 6 apart.
#define BODY(KS, CA, CX, NA, NX)                                               \
  {                                                                            \
    if ((KS) < 24) {                                                           \
      NA[0] = *reinterpret_cast<const short8*>(par + ((KS)+1)*32);             \
      NA[1] = *reinterpret_cast<const short8*>(par + ((KS)+1)*32 + 16);        \
      NA[2] = *reinterpret_cast<const short8*>(pai + ((KS)+1)*32);             \
      NA[3] = *reinterpret_cast<const short8*>(pai + ((KS)+1)*32 + 16);        \
      NX[0] = *reinterpret_cast<const short8*>(&sX[xoff + 0*6400 + ((KS)+1)*32]);      \
      NX[1] = *reinterpret_cast<const short8*>(&sX[xoff + 0*6400 + ((KS)+1)*32 + 16]); \
      NX[2] = *reinterpret_cast<const short8*>(&sX[xoff + 1*6400 + ((KS)+1)*32]);      \
      NX[3] = *reinterpret_cast<const short8*>(&sX[xoff + 1*6400 + ((KS)+1)*32 + 16]); \
      NX[4] = *reinterpret_cast<const short8*>(&sX[xoff + 2*6400 + ((KS)+1)*32]);      \
      NX[5] = *reinterpret_cast<const short8*>(&sX[xoff + 2*6400 + ((KS)+1)*32 + 16]); \
    }                                                                          \
    __builtin_amdgcn_s_setprio(1);                                             \
    MF32(CA[0], CX[0], acc_r[0]); MF32(CA[0], CX[2], acc_r[1]);                \
    MF32(CA[0], CX[4], acc_r[2]);                                              \
    MF32(CA[2], CX[0], acc_i[0]); MF32(CA[2], CX[2], acc_i[1]);                \
    MF32(CA[2], CX[4], acc_i[2]);                                              \
    MF32(CA[1], CX[1], acc_r[0]); MF32(CA[1], CX[3], acc_r[1]);                \
    MF32(CA[1], CX[5], acc_r[2]);                                              \
    MF32(CA[3], CX[1], acc_i[0]); MF32(CA[3], CX[3], acc_i[1]);                \
    MF32(CA[3], CX[5], acc_i[2]);                                              \
    __builtin_amdgcn_s_setprio(0);                                             \
  }

__global__ __launch_bounds__(256, 2)
void stft_mag_kernel(const short* __restrict__ xb,
                     const short* __restrict__ bb,
                     float* __restrict__ out) {
    __shared__ short sX[SLICE_SH];     // 80,000 B — 2 blocks/CU

    const int tid = threadIdx.x;

    // ---- bijective XCD-chunked swizzle (nwg=1463), f-fastest ----
    const int nwg = NTT * 7;
    const int q = nwg >> 3, r = nwg & 7;
    const int bid = blockIdx.x;
    const int xcd = bid & 7, idx = bid >> 3;
    const int wgid = (xcd < r ? xcd * (q + 1) : r * (q + 1) + (xcd - r) * q) + idx;
    const int t0 = (wgid / 7) * TT;
    const int f0 = (wgid % 7) * FT;

    const int lane = tid & 63;
    const int wid  = tid >> 6;
    const int wm   = wid >> 1;       // 0..1 -> which 32 freqs
    const int wn   = wid & 1;        // 0..1 -> which 96 frames
    const int l31  = lane & 31;
    const int lk   = lane >> 5;      // k-half selector

    // ---- stage sX: 19 full sweeps + 1 partial (tid<136), clamped tail ----
    {
        const int g0 = t0 * HOP + tid * 8;
        short* dst = sX + tid * 8;
        #pragma unroll
        for (int it = 0; it < 19; ++it) {
            int off = g0 + it * 2048;
            if (off > XBN - 8) off = XBN - 8;
            __builtin_amdgcn_global_load_lds((GU32)(xb + off),
                                             (LU32)(dst + it * 2048), 16, 0, 0);
        }
        if (tid < 136) {
            int off = g0 + 19 * 2048;
            if (off > XBN - 8) off = XBN - 8;
            __builtin_amdgcn_global_load_lds((GU32)(xb + off),
                                             (LU32)(dst + 19 * 2048), 16, 0, 0);
        }
    }

    // ---- A-fragment global base pointers (32x32x16: row=l31, k=lk*8+i) ----
    const short* par = bb + (size_t)(f0 + wm * 32 + l31) * 800 + lk * 8;   // real
    const short* pai = par + (size_t)448 * 800;                            // imag

    const int xoff = (wn * 96 + l31) * 200 + lk * 8;   // + ni*6400 + ks*32 (+16)

    f32x16 acc_r[3] = {};
    f32x16 acc_i[3] = {};

    short8 FAa[4], FAx[6], FBa[4], FBx[6];

    // A frags for ks=0 (global->reg, independent of LDS)
    FAa[0] = *reinterpret_cast<const short8*>(par);
    FAa[1] = *reinterpret_cast<const short8*>(par + 16);
    FAa[2] = *reinterpret_cast<const short8*>(pai);
    FAa[3] = *reinterpret_cast<const short8*>(pai + 16);

    // sX landed -> the ONLY barrier
    asm volatile("s_waitcnt vmcnt(0)" ::: "memory");
    __builtin_amdgcn_s_barrier();
    asm volatile("" ::: "memory");

    // X frags for ks=0
    FAx[0] = *reinterpret_cast<const short8*>(&sX[xoff + 0*6400]);
    FAx[1] = *reinterpret_cast<const short8*>(&sX[xoff + 0*6400 + 16]);
    FAx[2] = *reinterpret_cast<const short8*>(&sX[xoff + 1*6400]);
    FAx[3] = *reinterpret_cast<const short8*>(&sX[xoff + 1*6400 + 16]);
    FAx[4] = *reinterpret_cast<const short8*>(&sX[xoff + 2*6400]);
    FAx[5] = *reinterpret_cast<const short8*>(&sX[xoff + 2*6400 + 16]);

    // ---- barrier-free main pipeline: 25 steps ----
    #pragma unroll
    for (int jj = 0; jj < 12; ++jj) {
        BODY(2*jj,     FAa, FAx, FBa, FBx);
        BODY(2*jj + 1, FBa, FBx, FAa, FAx);
    }
    BODY(24, FAa, FAx, FBa, FBx);

    // ---- epilogue: magnitude + coalesced stores (32 lanes = 32 consecutive t) ----
    #pragma unroll
    for (int ni = 0; ni < 3; ++ni) {
        const int t = t0 + wn * 96 + ni * 32 + l31;
        if (t < NT) {
            #pragma unroll
            for (int reg = 0; reg < 16; ++reg) {
                const int row = (reg & 3) + 8 * (reg >> 2) + 4 * lk;
                const int f = f0 + wm * 32 + row;
                if (f < CUT) {
                    const float vr = acc_r[ni][reg];
                    const float vi = acc_i[ni][reg];
                    out[(size_t)f * NT + t] = sqrtf(vr * vr + vi * vi);
                }
            }
        }
    }
}

extern "C" void kernel_launch(void* const* d_in, const int* in_sizes, int n_in,
                              void* d_out, int out_size, void* d_ws, size_t ws_size,
                              hipStream_t stream) {
    const float* x     = (const float*)d_in[0];
    const float* basis = (const float*)d_in[1];
    float* out = (float*)d_out;

    short* xb = (short*)d_ws;
    short* bb = (short*)((char*)d_ws + BB_OFF);

    prep_x<<<2048, 256, 0, stream>>>(x, xb);
    prep_b<<<350, 256, 0, stream>>>(basis, bb);

    stft_mag_kernel<<<NTT * 7, 256, 0, stream>>>(xb, bb, out);
}

// Round 10
// 79.886 us; speedup vs baseline: 1.0225x; 1.0225x over previous
//
#include <hip/hip_runtime.h>

// STFT magnitude via bf16 MFMA GEMM.
// Round 10 (= round 9 + sqrtf fix): k-tiled basis layout bt[k2][896][16] so
// each A-fragment load is ONE dense 1024B region (16 cache lines vs 32
// sparse in round 8). Keeps 32x32x16 MFMA, TT=192, 2 blocks/CU, barrier-free
// main loop with distance-1 register prefetch (A: global->reg; X: LDS->reg).

#define FL   800
#define HOP  200
#define CUT  401
#define NS   8000000
#define NT   40001
#define KSTEPS 25            // 800/32

#define FT   64              // freq tile per block
#define TT   192             // frame tile per block
#define NTT  209             // ceil(40001/192)
#define SLICE_SH 40000       // sX shorts (need 39000)
#define XBN  8016000         // xb length in shorts
#define BB_OFF 16032000      // byte offset of bt in ws (= XBN*2)
#define KSTRIDE 28672        // shorts per k2-pair step: 2*896*16
#define FRAG1   14336        // shorts per single k2: 896*16
#define IMAG    7168         // shorts: 448*16 (imag fidx offset)

typedef short short8 __attribute__((ext_vector_type(8)));
typedef float float4v __attribute__((ext_vector_type(4)));
typedef float f32x16 __attribute__((ext_vector_type(16)));

#define GU32 const __attribute__((address_space(1))) unsigned int*
#define LU32 __attribute__((address_space(3))) unsigned int*

__device__ inline unsigned short f2bf(float f) {
    union { float f; unsigned u; } v; v.f = f;
    unsigned r = v.u + 0x7FFFu + ((v.u >> 16) & 1u);   // RNE
    return (unsigned short)(r >> 16);
}

// ---- prep 1: x (fp32) -> xb (bf16, reflect-padded by 400) ----
__global__ void prep_x(const float* __restrict__ x, short* __restrict__ xb) {
    const int n8 = XBN / 8;
    for (int j = blockIdx.x * blockDim.x + threadIdx.x; j < n8;
         j += gridDim.x * blockDim.x) {
        const int i = j * 8;
        const int s = i - 400;
        short8 o;
        if (s >= 0 && s + 7 < NS) {
            const float4v a = *reinterpret_cast<const float4v*>(x + s);
            const float4v b = *reinterpret_cast<const float4v*>(x + s + 4);
            o[0]=f2bf(a[0]); o[1]=f2bf(a[1]); o[2]=f2bf(a[2]); o[3]=f2bf(a[3]);
            o[4]=f2bf(b[0]); o[5]=f2bf(b[1]); o[6]=f2bf(b[2]); o[7]=f2bf(b[3]);
        } else {
            #pragma unroll
            for (int q = 0; q < 8; ++q) {
                int sq = s + q;
                if (sq < 0) sq = -sq;
                else if (sq >= NS) sq = 2 * NS - 2 - sq;
                o[q] = f2bf(x[sq]);
            }
        }
        *reinterpret_cast<short8*>(xb + i) = o;
    }
}

// ---- prep 2: basis (802x800 fp32) -> bt[k2][896][16] bf16 (k-tiled) ----
// linear short8 chunk j: k2 = j/1792, fidx = (j%1792)>>1, half = j&1
__global__ void prep_b(const float* __restrict__ basis, short* __restrict__ bt) {
    const int nch = 50 * 896 * 2;     // 89600
    for (int j = blockIdx.x * blockDim.x + threadIdx.x; j < nch;
         j += gridDim.x * blockDim.x) {
        const int k2   = j / 1792;
        const int rem  = j % 1792;
        const int fidx = rem >> 1;
        const int half = rem & 1;
        int src = -1;
        if (fidx < CUT) src = fidx;                                  // real
        else if (fidx >= 448 && fidx < 448 + CUT) src = fidx - 47;   // imag
        short8 o;
        if (src >= 0) {
            const float* p = basis + (size_t)src * 800 + k2 * 16 + half * 8;
            const float4v a = *reinterpret_cast<const float4v*>(p);
            const float4v b = *reinterpret_cast<const float4v*>(p + 4);
            o[0]=f2bf(a[0]); o[1]=f2bf(a[1]); o[2]=f2bf(a[2]); o[3]=f2bf(a[3]);
            o[4]=f2bf(b[0]); o[5]=f2bf(b[1]); o[6]=f2bf(b[2]); o[7]=f2bf(b[3]);
        } else {
            #pragma unroll
            for (int q = 0; q < 8; ++q) o[q] = 0;
        }
        *reinterpret_cast<short8*>(bt + (size_t)j * 8) = o;
    }
}

#define MF32(A, X, C) C = __builtin_amdgcn_mfma_f32_32x32x16_bf16((A), (X), (C), 0, 0, 0)

// One pipeline step. CA/CX = frags for step KS; NA/NX <- prefetch for KS+1.
// A-loads: each is one dense 1024B region from bt (16 lines, fully coalesced).
#define BODY(KS, CA, CX, NA, NX)                                               \
  {                                                                            \
    if ((KS) < 24) {                                                           \
      NA[0] = *reinterpret_cast<const short8*>(par + (size_t)((KS)+1)*KSTRIDE);         \
      NA[1] = *reinterpret_cast<const short8*>(par + (size_t)((KS)+1)*KSTRIDE + FRAG1); \
      NA[2] = *reinterpret_cast<const short8*>(pai + (size_t)((KS)+1)*KSTRIDE);         \
      NA[3] = *reinterpret_cast<const short8*>(pai + (size_t)((KS)+1)*KSTRIDE + FRAG1); \
      NX[0] = *reinterpret_cast<const short8*>(&sX[xoff + 0*6400 + ((KS)+1)*32]);      \
      NX[1] = *reinterpret_cast<const short8*>(&sX[xoff + 0*6400 + ((KS)+1)*32 + 16]); \
      NX[2] = *reinterpret_cast<const short8*>(&sX[xoff + 1*6400 + ((KS)+1)*32]);      \
      NX[3] = *reinterpret_cast<const short8*>(&sX[xoff + 1*6400 + ((KS)+1)*32 + 16]); \
      NX[4] = *reinterpret_cast<const short8*>(&sX[xoff + 2*6400 + ((KS)+1)*32]);      \
      NX[5] = *reinterpret_cast<const short8*>(&sX[xoff + 2*6400 + ((KS)+1)*32 + 16]); \
    }                                                                          \
    __builtin_amdgcn_s_setprio(1);                                             \
    MF32(CA[0], CX[0], acc_r[0]); MF32(CA[0], CX[2], acc_r[1]);                \
    MF32(CA[0], CX[4], acc_r[2]);                                              \
    MF32(CA[2], CX[0], acc_i[0]); MF32(CA[2], CX[2], acc_i[1]);                \
    MF32(CA[2], CX[4], acc_i[2]);                                              \
    MF32(CA[1], CX[1], acc_r[0]); MF32(CA[1], CX[3], acc_r[1]);                \
    MF32(CA[1], CX[5], acc_r[2]);                                              \
    MF32(CA[3], CX[1], acc_i[0]); MF32(CA[3], CX[3], acc_i[1]);                \
    MF32(CA[3], CX[5], acc_i[2]);                                              \
    __builtin_amdgcn_s_setprio(0);                                             \
  }

__global__ __launch_bounds__(256, 2)
void stft_mag_kernel(const short* __restrict__ xb,
                     const short* __restrict__ bt,
                     float* __restrict__ out) {
    __shared__ short sX[SLICE_SH];     // 80,000 B — 2 blocks/CU

    const int tid = threadIdx.x;

    // ---- bijective XCD-chunked swizzle (nwg=1463), f-fastest ----
    const int nwg = NTT * 7;
    const int q = nwg >> 3, r = nwg & 7;
    const int bid = blockIdx.x;
    const int xcd = bid & 7, idx = bid >> 3;
    const int wgid = (xcd < r ? xcd * (q + 1) : r * (q + 1) + (xcd - r) * q) + idx;
    const int t0 = (wgid / 7) * TT;
    const int f0 = (wgid % 7) * FT;

    const int lane = tid & 63;
    const int wid  = tid >> 6;
    const int wm   = wid >> 1;       // 0..1 -> which 32 freqs
    const int wn   = wid & 1;        // 0..1 -> which 96 frames
    const int l31  = lane & 31;
    const int lk   = lane >> 5;      // k-half selector

    // ---- stage sX: 19 full sweeps + 1 partial (tid<136), clamped tail ----
    {
        const int g0 = t0 * HOP + tid * 8;
        short* dst = sX + tid * 8;
        #pragma unroll
        for (int it = 0; it < 19; ++it) {
            int off = g0 + it * 2048;
            if (off > XBN - 8) off = XBN - 8;
            __builtin_amdgcn_global_load_lds((GU32)(xb + off),
                                             (LU32)(dst + it * 2048), 16, 0, 0);
        }
        if (tid < 136) {
            int off = g0 + 19 * 2048;
            if (off > XBN - 8) off = XBN - 8;
            __builtin_amdgcn_global_load_lds((GU32)(xb + off),
                                             (LU32)(dst + 19 * 2048), 16, 0, 0);
        }
    }

    // ---- A-fragment base pointers into bt[k2][896][16] ----
    // lane reads bt[2*ks + (frag)][fb][lk*8 .. +8]  (one dense 1KB per load)
    const int fb = f0 + wm * 32 + l31;
    const short* par = bt + (size_t)fb * 16 + lk * 8;          // real
    const short* pai = par + IMAG;                             // imag (fidx+448)

    const int xoff = (wn * 96 + l31) * 200 + lk * 8;   // + ni*6400 + ks*32 (+16)

    f32x16 acc_r[3] = {};
    f32x16 acc_i[3] = {};

    short8 FAa[4], FAx[6], FBa[4], FBx[6];

    // A frags for ks=0 (global->reg, independent of LDS)
    FAa[0] = *reinterpret_cast<const short8*>(par);
    FAa[1] = *reinterpret_cast<const short8*>(par + FRAG1);
    FAa[2] = *reinterpret_cast<const short8*>(pai);
    FAa[3] = *reinterpret_cast<const short8*>(pai + FRAG1);

    // sX landed -> the ONLY barrier
    asm volatile("s_waitcnt vmcnt(0)" ::: "memory");
    __builtin_amdgcn_s_barrier();
    asm volatile("" ::: "memory");

    // X frags for ks=0
    FAx[0] = *reinterpret_cast<const short8*>(&sX[xoff + 0*6400]);
    FAx[1] = *reinterpret_cast<const short8*>(&sX[xoff + 0*6400 + 16]);
    FAx[2] = *reinterpret_cast<const short8*>(&sX[xoff + 1*6400]);
    FAx[3] = *reinterpret_cast<const short8*>(&sX[xoff + 1*6400 + 16]);
    FAx[4] = *reinterpret_cast<const short8*>(&sX[xoff + 2*6400]);
    FAx[5] = *reinterpret_cast<const short8*>(&sX[xoff + 2*6400 + 16]);

    // ---- barrier-free main pipeline: 25 steps ----
    #pragma unroll
    for (int jj = 0; jj < 12; ++jj) {
        BODY(2*jj,     FAa, FAx, FBa, FBx);
        BODY(2*jj + 1, FBa, FBx, FAa, FAx);
    }
    BODY(24, FAa, FAx, FBa, FBx);

    // ---- epilogue: magnitude + coalesced stores (32 lanes = 32 consecutive t) ----
    #pragma unroll
    for (int ni = 0; ni < 3; ++ni) {
        const int t = t0 + wn * 96 + ni * 32 + l31;
        if (t < NT) {
            #pragma unroll
            for (int reg = 0; reg < 16; ++reg) {
                const int row = (reg & 3) + 8 * (reg >> 2) + 4 * lk;
                const int f = f0 + wm * 32 + row;
                if (f < CUT) {
                    const float vr = acc_r[ni][reg];
                    const float vi = acc_i[ni][reg];
                    out[(size_t)f * NT + t] = sqrtf(vr * vr + vi * vi);
                }
            }
        }
    }
}

extern "C" void kernel_launch(void* const* d_in, const int* in_sizes, int n_in,
                              void* d_out, int out_size, void* d_ws, size_t ws_size,
                              hipStream_t stream) {
    const float* x     = (const float*)d_in[0];
    const float* basis = (const float*)d_in[1];
    float* out = (float*)d_out;

    short* xb = (short*)d_ws;
    short* bt = (short*)((char*)d_ws + BB_OFF);

    prep_x<<<2048, 256, 0, stream>>>(x, xb);
    prep_b<<<350, 256, 0, stream>>>(basis, bt);

    stft_mag_kernel<<<NTT * 7, 256, 0, stream>>>(xb, bt, out);
}

// Round 11
// 78.274 us; speedup vs baseline: 1.0436x; 1.0206x over previous
//
#include <hip/hip_runtime.h>

// STFT magnitude via bf16 MFMA GEMM.
// Round 11: TLP fix — TT=128 (sX 53KB) => 3 blocks/CU = 3 waves/SIMD (+50%
// latency coverage vs round 10's 2). Wave tile 32F x 64N, 8 MFMA : 8 loads
// per step. Keeps k-tiled bt layout, barrier-free main loop, distance-1
// register prefetch, XCD-chunked swizzle.

#define FL   800
#define HOP  200
#define CUT  401
#define NS   8000000
#define NT   40001
#define KSTEPS 25            // 800/32

#define FT   64              // freq tile per block
#define TT   128             // frame tile per block
#define NTT  313             // ceil(40001/128)
#define SLICE_SH 26624       // sX shorts: 13 sweeps * 2048 (need 26200)
#define XBN  8016000         // xb length in shorts
#define BB_OFF 16032000      // byte offset of bt in ws (= XBN*2)
#define KSTRIDE 28672        // shorts per k2-pair step: 2*896*16
#define FRAG1   14336        // shorts per single k2: 896*16
#define IMAG    7168         // shorts: 448*16 (imag fidx offset)

typedef short short8 __attribute__((ext_vector_type(8)));
typedef float float4v __attribute__((ext_vector_type(4)));
typedef float f32x16 __attribute__((ext_vector_type(16)));

#define GU32 const __attribute__((address_space(1))) unsigned int*
#define LU32 __attribute__((address_space(3))) unsigned int*

__device__ inline unsigned short f2bf(float f) {
    union { float f; unsigned u; } v; v.f = f;
    unsigned r = v.u + 0x7FFFu + ((v.u >> 16) & 1u);   // RNE
    return (unsigned short)(r >> 16);
}

// ---- prep 1: x (fp32) -> xb (bf16, reflect-padded by 400) ----
__global__ void prep_x(const float* __restrict__ x, short* __restrict__ xb) {
    const int n8 = XBN / 8;
    for (int j = blockIdx.x * blockDim.x + threadIdx.x; j < n8;
         j += gridDim.x * blockDim.x) {
        const int i = j * 8;
        const int s = i - 400;
        short8 o;
        if (s >= 0 && s + 7 < NS) {
            const float4v a = *reinterpret_cast<const float4v*>(x + s);
            const float4v b = *reinterpret_cast<const float4v*>(x + s + 4);
            o[0]=f2bf(a[0]); o[1]=f2bf(a[1]); o[2]=f2bf(a[2]); o[3]=f2bf(a[3]);
            o[4]=f2bf(b[0]); o[5]=f2bf(b[1]); o[6]=f2bf(b[2]); o[7]=f2bf(b[3]);
        } else {
            #pragma unroll
            for (int q = 0; q < 8; ++q) {
                int sq = s + q;
                if (sq < 0) sq = -sq;
                else if (sq >= NS) sq = 2 * NS - 2 - sq;
                o[q] = f2bf(x[sq]);
            }
        }
        *reinterpret_cast<short8*>(xb + i) = o;
    }
}

// ---- prep 2: basis (802x800 fp32) -> bt[k2][896][16] bf16 (k-tiled) ----
__global__ void prep_b(const float* __restrict__ basis, short* __restrict__ bt) {
    const int nch = 50 * 896 * 2;     // 89600
    for (int j = blockIdx.x * blockDim.x + threadIdx.x; j < nch;
         j += gridDim.x * blockDim.x) {
        const int k2   = j / 1792;
        const int rem  = j % 1792;
        const int fidx = rem >> 1;
        const int half = rem & 1;
        int src = -1;
        if (fidx < CUT) src = fidx;                                  // real
        else if (fidx >= 448 && fidx < 448 + CUT) src = fidx - 47;   // imag
        short8 o;
        if (src >= 0) {
            const float* p = basis + (size_t)src * 800 + k2 * 16 + half * 8;
            const float4v a = *reinterpret_cast<const float4v*>(p);
            const float4v b = *reinterpret_cast<const float4v*>(p + 4);
            o[0]=f2bf(a[0]); o[1]=f2bf(a[1]); o[2]=f2bf(a[2]); o[3]=f2bf(a[3]);
            o[4]=f2bf(b[0]); o[5]=f2bf(b[1]); o[6]=f2bf(b[2]); o[7]=f2bf(b[3]);
        } else {
            #pragma unroll
            for (int q = 0; q < 8; ++q) o[q] = 0;
        }
        *reinterpret_cast<short8*>(bt + (size_t)j * 8) = o;
    }
}

#define MF32(A, X, C) C = __builtin_amdgcn_mfma_f32_32x32x16_bf16((A), (X), (C), 0, 0, 0)

// One pipeline step. CA/CX = frags for step KS; NA/NX <- prefetch for KS+1.
#define BODY(KS, CA, CX, NA, NX)                                               \
  {                                                                            \
    if ((KS) < 24) {                                                           \
      NA[0] = *reinterpret_cast<const short8*>(par + (size_t)((KS)+1)*KSTRIDE);         \
      NA[1] = *reinterpret_cast<const short8*>(par + (size_t)((KS)+1)*KSTRIDE + FRAG1); \
      NA[2] = *reinterpret_cast<const short8*>(pai + (size_t)((KS)+1)*KSTRIDE);         \
      NA[3] = *reinterpret_cast<const short8*>(pai + (size_t)((KS)+1)*KSTRIDE + FRAG1); \
      NX[0] = *reinterpret_cast<const short8*>(&sX[xoff + 0*6400 + ((KS)+1)*32]);      \
      NX[1] = *reinterpret_cast<const short8*>(&sX[xoff + 0*6400 + ((KS)+1)*32 + 16]); \
      NX[2] = *reinterpret_cast<const short8*>(&sX[xoff + 1*6400 + ((KS)+1)*32]);      \
      NX[3] = *reinterpret_cast<const short8*>(&sX[xoff + 1*6400 + ((KS)+1)*32 + 16]); \
    }                                                                          \
    __builtin_amdgcn_s_setprio(1);                                             \
    MF32(CA[0], CX[0], acc_r[0]); MF32(CA[0], CX[2], acc_r[1]);                \
    MF32(CA[2], CX[0], acc_i[0]); MF32(CA[2], CX[2], acc_i[1]);                \
    MF32(CA[1], CX[1], acc_r[0]); MF32(CA[1], CX[3], acc_r[1]);                \
    MF32(CA[3], CX[1], acc_i[0]); MF32(CA[3], CX[3], acc_i[1]);                \
    __builtin_amdgcn_s_setprio(0);                                             \
  }

__global__ __launch_bounds__(256, 3)
void stft_mag_kernel(const short* __restrict__ xb,
                     const short* __restrict__ bt,
                     float* __restrict__ out) {
    __shared__ short sX[SLICE_SH];     // 53,248 B — 3 blocks/CU

    const int tid = threadIdx.x;

    // ---- bijective XCD-chunked swizzle (nwg=2191), f-fastest ----
    const int nwg = NTT * 7;
    const int q = nwg >> 3, r = nwg & 7;
    const int bid = blockIdx.x;
    const int xcd = bid & 7, idx = bid >> 3;
    const int wgid = (xcd < r ? xcd * (q + 1) : r * (q + 1) + (xcd - r) * q) + idx;
    const int t0 = (wgid / 7) * TT;
    const int f0 = (wgid % 7) * FT;

    const int lane = tid & 63;
    const int wid  = tid >> 6;
    const int wm   = wid >> 1;       // 0..1 -> which 32 freqs
    const int wn   = wid & 1;        // 0..1 -> which 64 frames
    const int l31  = lane & 31;
    const int lk   = lane >> 5;      // k-half selector

    // ---- stage sX: 13 sweeps of global_load_lds width-16, clamped ----
    {
        const int g0 = t0 * HOP + tid * 8;
        short* dst = sX + tid * 8;
        #pragma unroll
        for (int it = 0; it < 13; ++it) {
            int off = g0 + it * 2048;
            if (off > XBN - 8) off = XBN - 8;   // garbage cols masked at store
            __builtin_amdgcn_global_load_lds((GU32)(xb + off),
                                             (LU32)(dst + it * 2048), 16, 0, 0);
        }
    }

    // ---- A-fragment base pointers into bt[k2][896][16] ----
    const int fb = f0 + wm * 32 + l31;
    const short* par = bt + (size_t)fb * 16 + lk * 8;          // real
    const short* pai = par + IMAG;                             // imag

    const int xoff = (wn * 64 + l31) * 200 + lk * 8;   // + ni*6400 + ks*32 (+16)

    f32x16 acc_r[2] = {};
    f32x16 acc_i[2] = {};

    short8 FAa[4], FAx[4], FBa[4], FBx[4];

    // A frags for ks=0 (global->reg, independent of LDS)
    FAa[0] = *reinterpret_cast<const short8*>(par);
    FAa[1] = *reinterpret_cast<const short8*>(par + FRAG1);
    FAa[2] = *reinterpret_cast<const short8*>(pai);
    FAa[3] = *reinterpret_cast<const short8*>(pai + FRAG1);

    // sX landed -> the ONLY barrier
    asm volatile("s_waitcnt vmcnt(0)" ::: "memory");
    __builtin_amdgcn_s_barrier();
    asm volatile("" ::: "memory");

    // X frags for ks=0
    FAx[0] = *reinterpret_cast<const short8*>(&sX[xoff + 0*6400]);
    FAx[1] = *reinterpret_cast<const short8*>(&sX[xoff + 0*6400 + 16]);
    FAx[2] = *reinterpret_cast<const short8*>(&sX[xoff + 1*6400]);
    FAx[3] = *reinterpret_cast<const short8*>(&sX[xoff + 1*6400 + 16]);

    // ---- barrier-free main pipeline: 25 steps ----
    #pragma unroll
    for (int jj = 0; jj < 12; ++jj) {
        BODY(2*jj,     FAa, FAx, FBa, FBx);
        BODY(2*jj + 1, FBa, FBx, FAa, FAx);
    }
    BODY(24, FAa, FAx, FBa, FBx);

    // ---- epilogue: magnitude + coalesced stores (32 lanes = 32 consecutive t) ----
    #pragma unroll
    for (int ni = 0; ni < 2; ++ni) {
        const int t = t0 + wn * 64 + ni * 32 + l31;
        if (t < NT) {
            #pragma unroll
            for (int reg = 0; reg < 16; ++reg) {
                const int row = (reg & 3) + 8 * (reg >> 2) + 4 * lk;
                const int f = f0 + wm * 32 + row;
                if (f < CUT) {
                    const float vr = acc_r[ni][reg];
                    const float vi = acc_i[ni][reg];
                    out[(size_t)f * NT + t] = sqrtf(vr * vr + vi * vi);
                }
            }
        }
    }
}

extern "C" void kernel_launch(void* const* d_in, const int* in_sizes, int n_in,
                              void* d_out, int out_size, void* d_ws, size_t ws_size,
                              hipStream_t stream) {
    const float* x     = (const float*)d_in[0];
    const float* basis = (const float*)d_in[1];
    float* out = (float*)d_out;

    short* xb = (short*)d_ws;
    short* bt = (short*)((char*)d_ws + BB_OFF);

    prep_x<<<2048, 256, 0, stream>>>(x, xb);
    prep_b<<<350, 256, 0, stream>>>(basis, bt);

    stft_mag_kernel<<<NTT * 7, 256, 0, stream>>>(xb, bt, out);
}